// Round 13
// baseline (149.158 us; speedup 1.0000x reference)
//
#include <hip/hip_runtime.h>
#include <hip/hip_bf16.h>

#define TOKENS 16384
#define NEXP 8
#define INF 512
#define OUTF 512

#define BM 64
#define BN 128
#define BK 64
#define NST (INF / BK)     // 8 K-steps
#define MAXMT 40           // 2560 rows/expert; counts ~2048±42(σ) -> +12σ safe
#define EROWS (MAXMT * BM)
#define GRID 768           // 8e x 4nt x 24 slots; capacity >= 3/CU -> all resident

using f32x4 = __attribute__((ext_vector_type(4))) float;
using bfrag = __attribute__((ext_vector_type(8))) __bf16;
using s8v   = __attribute__((ext_vector_type(8))) short;

// fp32 -> bf16 RNE
__device__ __forceinline__ short f2bf(float f) {
  union { float f; unsigned u; } v; v.f = f;
  unsigned r = v.u + 0x7fffu + ((v.u >> 16) & 1u);
  return (short)(r >> 16);
}

__device__ __forceinline__ void gload16(const void* g, void* l) {
  __builtin_amdgcn_global_load_lds(
      (const __attribute__((address_space(1))) unsigned int*)g,
      (__attribute__((address_space(3))) unsigned int*)l, 16, 0, 0);
}

__device__ __forceinline__ s8v pack8(float4 a, float4 b) {
  s8v p;
  p[0] = f2bf(a.x); p[1] = f2bf(a.y); p[2] = f2bf(a.z); p[3] = f2bf(a.w);
  p[4] = f2bf(b.x); p[5] = f2bf(b.y); p[6] = f2bf(b.z); p[7] = f2bf(b.w);
  return p;
}

__device__ __forceinline__ bfrag cvt8(f32x4 lo, f32x4 hi) {
  bfrag r;
  r[0] = (__bf16)lo[0]; r[1] = (__bf16)lo[1];
  r[2] = (__bf16)lo[2]; r[3] = (__bf16)lo[3];
  r[4] = (__bf16)hi[0]; r[5] = (__bf16)hi[1];
  r[6] = (__bf16)hi[2]; r[7] = (__bf16)hi[3];
  return r;
}

// Single fused persistent kernel.
// Phase 1: blocks 0..63 scatter tokens (block-aggregated atomics); ALL blocks
//   grid-stride convert weight fp32->bf16. threadfence + arrive + agent-scope
//   spin barrier (all GRID blocks co-resident: LDS 33KB -> >=4 slots/CU by
//   LDS, >=3 by launch_bounds -> capacity >= GRID).
// Phase 2: R11-proven gemm7 body, persistent mt loop (stride 24).
//   perm/cursor read via agent-scope atomic loads (order nondeterministic
//   across replays; plain reads could hit stale XCD-L2 lines). wbf/inp/weight
//   are value-identical across replays -> plain reads safe.
__global__ __launch_bounds__(256, 3)
void k_fused(const float* __restrict__ inp, const int* __restrict__ gate,
             const float* __restrict__ w, float* __restrict__ out,
             int* __restrict__ cursor, int* __restrict__ perm,
             short* __restrict__ wbf, int* __restrict__ bar) {
  const int bid = blockIdx.x, tid = threadIdx.x;

  __shared__ int lc[NEXP], lb[NEXP];
  __shared__ __align__(16) char Albs[BM * BK * 4];   // 16 KB fp32 A
  __shared__ __align__(16) char Blbs[BN * BK * 2];   // 16 KB bf16 B
  __shared__ int toks[BM];

  // ---------------- phase 1: scatter + weight convert ----------------
  if (bid < 64) {
    if (tid < NEXP) lc[tid] = 0;
    __syncthreads();
    int t = bid * 256 + tid;
    int e = gate[t];
    int ls = atomicAdd(&lc[e], 1);
    __syncthreads();
    if (tid < NEXP) lb[tid] = lc[tid] ? atomicAdd(&cursor[tid], lc[tid]) : 0;
    __syncthreads();
    perm[e * EROWS + lb[e] + ls] = t;
  }
  for (int idx = bid * 256 + tid; idx < (NEXP * OUTF * INF) / 8;
       idx += GRID * 256) {
    const float4* src = (const float4*)w + (size_t)idx * 2;
    ((s8v*)wbf)[idx] = pack8(src[0], src[1]);
  }

  __threadfence();           // flush this thread's perm/wbf stores to device
  __syncthreads();
  if (tid == 0) {
    atomicAdd(bar, 1);       // device-scope arrive
    while (__hip_atomic_load(bar, __ATOMIC_RELAXED,
                             __HIP_MEMORY_SCOPE_AGENT) < GRID)
      __builtin_amdgcn_s_sleep(2);
  }
  __syncthreads();

  // ---------------- phase 2: grouped GEMM (R11 body, persistent) -------
  const int e  = bid & 7;
  const int nt = (bid >> 3) & 3;
  const int cnt = __hip_atomic_load(&cursor[e], __ATOMIC_RELAXED,
                                    __HIP_MEMORY_SCOPE_AGENT);

  const int lane = tid & 63;
  const int wid  = tid >> 6;
  const int wr = wid >> 1, wc = wid & 1;
  const int lr = lane & 15;
  const int lg = lane >> 4;

  // B DMA geometry (mt-invariant, R11-proven): 4 sites; chunk = s*256+tid ->
  // row = s*32+(tid>>3), cphys = tid&7; source clog = cphys ^ (row&7).
  const short* Wbase = wbf + ((size_t)e * OUTF + (size_t)nt * BN) * INF;
  const short* bgp[4];
#pragma unroll
  for (int s = 0; s < 4; s++) {
    int row  = s * 32 + (tid >> 3);
    int clog = (tid & 7) ^ (row & 7);
    bgp[s] = Wbase + (size_t)row * INF + clog * 8;
  }

  for (int mt = bid >> 5; mt < MAXMT; mt += 24) {
    if (mt * BM >= cnt) break;
    const int m_valid = min(BM, cnt - mt * BM);

    __syncthreads();   // prev iter's epilogue done before toks overwrite
    if (tid < BM) {
      int idx = e * EROWS + mt * BM + ((tid < m_valid) ? tid : 0);
      toks[tid] = __hip_atomic_load(&perm[idx], __ATOMIC_RELAXED,
                                    __HIP_MEMORY_SCOPE_AGENT);
    }
    __syncthreads();

    // A DMA geometry (R11-proven): 4 sites; chunk = s*256+tid ->
    // row = s*16+(tid>>4), cphys = tid&15; source clog = cphys ^ (row&15).
    const float* agp[4];
#pragma unroll
    for (int s = 0; s < 4; s++) {
      int row  = s * 16 + (tid >> 4);
      int clog = (tid & 15) ^ (row & 15);
      agp[s] = inp + (size_t)toks[row] * INF + clog * 4;
    }

    f32x4 acc[2][4];
#pragma unroll
    for (int m = 0; m < 2; m++)
#pragma unroll
      for (int j = 0; j < 4; j++) acc[m][j] = (f32x4)0.0f;

    for (int t = 0; t < NST; t++) {
#pragma unroll
      for (int s = 0; s < 4; s++)
        gload16(agp[s] + t * BK, Albs + s * 4096 + tid * 16);
#pragma unroll
      for (int s = 0; s < 4; s++)
        gload16(bgp[s] + t * BK, Blbs + s * 4096 + tid * 16);
      __syncthreads();   // drain DMA

#pragma unroll
      for (int ks = 0; ks < 2; ks++) {
        bfrag af[2], bv[4];
#pragma unroll
        for (int m = 0; m < 2; m++) {
          int row = wr * 32 + m * 16 + lr;
          int c0 = (ks * 8 + lg * 2) ^ (row & 15);
          int c1 = (ks * 8 + lg * 2 + 1) ^ (row & 15);
          f32x4 lo = *(const f32x4*)(Albs + row * 256 + c0 * 16);
          f32x4 hi = *(const f32x4*)(Albs + row * 256 + c1 * 16);
          af[m] = cvt8(lo, hi);
        }
#pragma unroll
        for (int j = 0; j < 4; j++) {
          int row = wc * 64 + j * 16 + lr;
          int c = (ks * 4 + lg) ^ (row & 7);
          bv[j] = *(const bfrag*)(Blbs + row * 128 + c * 16);
        }
#pragma unroll
        for (int m = 0; m < 2; m++)
#pragma unroll
          for (int j = 0; j < 4; j++)
            acc[m][j] = __builtin_amdgcn_mfma_f32_16x16x32_bf16(af[m], bv[j],
                                                                acc[m][j],
                                                                0, 0, 0);
      }
      if (t + 1 < NST) __syncthreads();
    }

    // epilogue: C/D col=lane&15, row=(lane>>4)*4+reg (proven)
#pragma unroll
    for (int m = 0; m < 2; m++) {
#pragma unroll
      for (int r = 0; r < 4; r++) {
        int rowE = wr * 32 + m * 16 + lg * 4 + r;
        if (rowE < m_valid) {
          float* orow = out + (size_t)toks[rowE] * OUTF + (size_t)nt * BN +
                        (size_t)wc * 64 + lr;
#pragma unroll
          for (int j = 0; j < 4; j++) orow[j * 16] = acc[m][j][r];
        }
      }
    }
  }
}

extern "C" void kernel_launch(void* const* d_in, const int* in_sizes, int n_in,
                              void* d_out, int out_size, void* d_ws, size_t ws_size,
                              hipStream_t stream) {
  (void)in_sizes; (void)n_in; (void)out_size; (void)ws_size;
  const float* inp    = (const float*)d_in[0];
  const int*   gate   = (const int*)d_in[1];
  const float* weight = (const float*)d_in[2];
  float* out = (float*)d_out;

  char* ws = (char*)d_ws;
  int*   cursor = (int*)ws;                    // 8 ints
  int*   bar    = (int*)(ws + 64);             // barrier counter
  int*   perm   = (int*)(ws + 4096);           // 8*2560*4 = 80 KB
  short* wbf    = (short*)(ws + (1 << 20));    // 4 MB bf16 weight

  hipMemsetAsync(ws, 0, 128, stream);          // zero cursor + bar
  k_fused<<<GRID, 256, 0, stream>>>(inp, gate, weight, out, cursor, perm,
                                    wbf, bar);
}

// Round 14
// 36.588 us; speedup vs baseline: 4.0767x; 4.0767x over previous
//
#include <hip/hip_runtime.h>
#include <hip/hip_bf16.h>

#define TOKENS 16384
#define NEXP 8
#define INF 512
#define OUTF 512

#define BM 64
#define BN 128
#define BK 64
#define NST (INF / BK)     // 8 K-steps
#define MAXMT 40           // 2560 rows/expert; counts ~2048±42(σ) -> +12σ safe
#define EROWS (MAXMT * BM)

using f32x4 = __attribute__((ext_vector_type(4))) float;
using bfrag = __attribute__((ext_vector_type(8))) __bf16;
using s8v   = __attribute__((ext_vector_type(8))) short;

// fp32 -> bf16 RNE
__device__ __forceinline__ short f2bf(float f) {
  union { float f; unsigned u; } v; v.f = f;
  unsigned r = v.u + 0x7fffu + ((v.u >> 16) & 1u);
  return (short)(r >> 16);
}

__device__ __forceinline__ void gload16(const void* g, void* l) {
  __builtin_amdgcn_global_load_lds(
      (const __attribute__((address_space(1))) unsigned int*)g,
      (__attribute__((address_space(3))) unsigned int*)l, 16, 0, 0);
}

__device__ __forceinline__ s8v pack8(float4 a, float4 b) {
  s8v p;
  p[0] = f2bf(a.x); p[1] = f2bf(a.y); p[2] = f2bf(a.z); p[3] = f2bf(a.w);
  p[4] = f2bf(b.x); p[5] = f2bf(b.y); p[6] = f2bf(b.z); p[7] = f2bf(b.w);
  return p;
}

// Fused prep (cursor pre-zeroed by memsetAsync):
//   blocks 0..63      : scatter tokens by expert (block-aggregated atomics)
//   blocks 64..1087   : weight fp32 -> bf16  (wbf, [E][O][I] contiguous)
//   blocks 1088..5183 : inp fp32 -> bf16     (inpb, TOKEN ORDER — no gather)
__global__ void k_prep(const int* __restrict__ gate, int* __restrict__ cursor,
                       int* __restrict__ perm, const float* __restrict__ w,
                       s8v* __restrict__ wb, const float* __restrict__ inp,
                       s8v* __restrict__ inpb) {
  __shared__ int lc[NEXP], lb[NEXP];
  const int bid = blockIdx.x, tid = threadIdx.x;
  if (bid < 64) {
    if (tid < NEXP) lc[tid] = 0;
    __syncthreads();
    int t = bid * 256 + tid;
    int e = gate[t];
    int ls = atomicAdd(&lc[e], 1);
    __syncthreads();
    if (tid < NEXP) lb[tid] = lc[tid] ? atomicAdd(&cursor[tid], lc[tid]) : 0;
    __syncthreads();
    perm[e * EROWS + lb[e] + ls] = t;
  } else if (bid < 1088) {
    int idx = (bid - 64) * 256 + tid;
    const float4* src = (const float4*)w + (size_t)idx * 2;
    wb[idx] = pack8(src[0], src[1]);
  } else {
    int idx = (bid - 1088) * 256 + tid;        // 4096 blocks, exact cover
    const float4* src = (const float4*)inp + (size_t)idx * 2;
    inpb[idx] = pack8(src[0], src[1]);
  }
}

// Grouped GEMM — R11-proven structure with bf16 A (halved staging bytes).
// 64x128 tile, BK=64, 1-phase single-buffer, plain __syncthreads, ~1024
// active blocks (4/CU by LDS 24.25KB). bid = e + 8*(nt + 4*mt): e -> XCD
// (B_e L2-hot); 4 nt-siblings of an A-tile concurrent on the same XCD.
// A & B both: 8 chunks/row of 16B, swizzle both-sides clog = c ^ (row&7)
// (the R11-proven B pattern, now shared by A since A is bf16 too).
__global__ __launch_bounds__(256, 4)
void moe_gemm9(const short* __restrict__ inpb, const short* __restrict__ wbf,
               const int* __restrict__ cursor, const int* __restrict__ perm,
               float* __restrict__ out) {
  const int bid = blockIdx.x;
  const int e  = bid & 7;
  const int nt = (bid >> 3) & 3;
  const int mt = bid >> 5;
  const int cnt = cursor[e];
  if (mt * BM >= cnt) return;
  const int m_valid = min(BM, cnt - mt * BM);
  const int* pb = perm + e * EROWS + mt * BM;

  __shared__ __align__(16) char Albs[BM * BK * 2];   //  8 KB bf16 A
  __shared__ __align__(16) char Blbs[BN * BK * 2];   // 16 KB bf16 B
  __shared__ int toks[BM];

  const int tid = threadIdx.x;
  if (tid < BM) toks[tid] = pb[(tid < m_valid) ? tid : 0];
  __syncthreads();

  const int lane = tid & 63;
  const int wid  = tid >> 6;
  const int wr = wid >> 1, wc = wid & 1;   // wave: rows wr*32..+31, cols wc*64..+63
  const int lr = lane & 15;
  const int lg = lane >> 4;

  // ---- A DMA geometry: 2 sites; chunk = s*256+tid -> row = s*32+(tid>>3),
  //      cphys = tid&7; source clog = cphys ^ (row&7); dest linear.
  const short* agp[2];
#pragma unroll
  for (int s = 0; s < 2; s++) {
    int row  = s * 32 + (tid >> 3);
    int clog = (tid & 7) ^ (row & 7);
    agp[s] = inpb + (size_t)toks[row] * INF + clog * 8;
  }

  // ---- B DMA geometry (R11-proven): 4 sites; row = s*32+(tid>>3),
  //      cphys = tid&7; source clog = cphys ^ (row&7); dest linear.
  const short* Wbase = wbf + ((size_t)e * OUTF + (size_t)nt * BN) * INF;
  const short* bgp[4];
#pragma unroll
  for (int s = 0; s < 4; s++) {
    int row  = s * 32 + (tid >> 3);
    int clog = (tid & 7) ^ (row & 7);
    bgp[s] = Wbase + (size_t)row * INF + clog * 8;
  }

  f32x4 acc[2][4];
#pragma unroll
  for (int m = 0; m < 2; m++)
#pragma unroll
    for (int j = 0; j < 4; j++) acc[m][j] = (f32x4)0.0f;

  for (int t = 0; t < NST; t++) {
    // ---- stage tile t (6 homogeneous gload16/thread) ----
#pragma unroll
    for (int s = 0; s < 2; s++)
      gload16(agp[s] + t * BK, Albs + s * 4096 + tid * 16);
#pragma unroll
    for (int s = 0; s < 4; s++)
      gload16(bgp[s] + t * BK, Blbs + s * 4096 + tid * 16);
    __syncthreads();   // drain DMA

    // ---- compute (2 ks x 2 m x 4 n = 16 MFMA/wave) ----
#pragma unroll
    for (int ks = 0; ks < 2; ks++) {
      bfrag af[2], bv[4];
#pragma unroll
      for (int m = 0; m < 2; m++) {
        int row = wr * 32 + m * 16 + lr;
        int c = (ks * 4 + lg) ^ (row & 7);
        af[m] = *(const bfrag*)(Albs + row * 128 + c * 16);
      }
#pragma unroll
      for (int j = 0; j < 4; j++) {
        int row = wc * 64 + j * 16 + lr;
        int c = (ks * 4 + lg) ^ (row & 7);
        bv[j] = *(const bfrag*)(Blbs + row * 128 + c * 16);
      }
#pragma unroll
      for (int m = 0; m < 2; m++)
#pragma unroll
        for (int j = 0; j < 4; j++)
          acc[m][j] = __builtin_amdgcn_mfma_f32_16x16x32_bf16(af[m], bv[j],
                                                              acc[m][j], 0, 0, 0);
    }
    if (t + 1 < NST) __syncthreads();  // reads done before next overwrite
  }

  // ---- epilogue: C/D col=lane&15, row=(lane>>4)*4+reg (proven) ----
#pragma unroll
  for (int m = 0; m < 2; m++) {
#pragma unroll
    for (int r = 0; r < 4; r++) {
      int rowE = wr * 32 + m * 16 + lg * 4 + r;
      if (rowE < m_valid) {
        float* orow = out + (size_t)toks[rowE] * OUTF + (size_t)nt * BN +
                      (size_t)wc * 64 + lr;
#pragma unroll
        for (int j = 0; j < 4; j++) orow[j * 16] = acc[m][j][r];
      }
    }
  }
}

extern "C" void kernel_launch(void* const* d_in, const int* in_sizes, int n_in,
                              void* d_out, int out_size, void* d_ws, size_t ws_size,
                              hipStream_t stream) {
  (void)in_sizes; (void)n_in; (void)out_size; (void)ws_size;
  const float* inp    = (const float*)d_in[0];
  const int*   gate   = (const int*)d_in[1];
  const float* weight = (const float*)d_in[2];
  float* out = (float*)d_out;

  char* ws = (char*)d_ws;
  int*   cursor = (int*)ws;                    // 64 B
  int*   perm   = (int*)(ws + 4096);           // 8*2560*4 = 80 KB
  short* wbf    = (short*)(ws + (1 << 20));    // 4 MB bf16 weight
  short* inpb   = (short*)(ws + (8 << 20));    // 16.7 MB bf16 inp (token order)

  hipMemsetAsync(cursor, 0, 64, stream);
  k_prep<<<1088 + (TOKENS * INF) / (256 * 8), 256, 0, stream>>>(
      gate, cursor, perm, weight, (s8v*)wbf, inp, (s8v*)inpb);
  moe_gemm9<<<NEXP * 4 * MAXMT, 256, 0, stream>>>(inpb, wbf, cursor, perm, out);
}

// Round 15
// 36.502 us; speedup vs baseline: 4.0863x; 1.0024x over previous
//
#include <hip/hip_runtime.h>
#include <hip/hip_bf16.h>

#define TOKENS 16384
#define NEXP 8
#define INF 512
#define OUTF 512

#define BM 128
#define BN 128
#define BK 64
#define NST (INF / BK)     // 8 K-steps
#define MAXMT 20           // 2560 rows/expert; counts ~2048±42(σ) -> +12σ safe
#define EROWS (MAXMT * BM)

using f32x4 = __attribute__((ext_vector_type(4))) float;
using bfrag = __attribute__((ext_vector_type(8))) __bf16;
using s8v   = __attribute__((ext_vector_type(8))) short;

// fp32 -> bf16 RNE
__device__ __forceinline__ short f2bf(float f) {
  union { float f; unsigned u; } v; v.f = f;
  unsigned r = v.u + 0x7fffu + ((v.u >> 16) & 1u);
  return (short)(r >> 16);
}

__device__ __forceinline__ void gload16(const void* g, void* l) {
  __builtin_amdgcn_global_load_lds(
      (const __attribute__((address_space(1))) unsigned int*)g,
      (__attribute__((address_space(3))) unsigned int*)l, 16, 0, 0);
}

__device__ __forceinline__ s8v pack8(float4 a, float4 b) {
  s8v p;
  p[0] = f2bf(a.x); p[1] = f2bf(a.y); p[2] = f2bf(a.z); p[3] = f2bf(a.w);
  p[4] = f2bf(b.x); p[5] = f2bf(b.y); p[6] = f2bf(b.z); p[7] = f2bf(b.w);
  return p;
}

// Fused prep (cursor pre-zeroed by memsetAsync):
//   blocks 0..63      : scatter tokens by expert (block-aggregated atomics)
//   blocks 64..1087   : weight fp32 -> bf16  (wbf, [E][O][I] contiguous)
//   blocks 1088..5183 : inp fp32 -> bf16     (inpb, TOKEN ORDER — no gather)
__global__ void k_prep(const int* __restrict__ gate, int* __restrict__ cursor,
                       int* __restrict__ perm, const float* __restrict__ w,
                       s8v* __restrict__ wb, const float* __restrict__ inp,
                       s8v* __restrict__ inpb) {
  __shared__ int lc[NEXP], lb[NEXP];
  const int bid = blockIdx.x, tid = threadIdx.x;
  if (bid < 64) {
    if (tid < NEXP) lc[tid] = 0;
    __syncthreads();
    int t = bid * 256 + tid;
    int e = gate[t];
    int ls = atomicAdd(&lc[e], 1);
    __syncthreads();
    if (tid < NEXP) lb[tid] = lc[tid] ? atomicAdd(&cursor[tid], lc[tid]) : 0;
    __syncthreads();
    perm[e * EROWS + lb[e] + ls] = t;
  } else if (bid < 1088) {
    int idx = (bid - 64) * 256 + tid;
    const float4* src = (const float4*)w + (size_t)idx * 2;
    wb[idx] = pack8(src[0], src[1]);
  } else {
    int idx = (bid - 1088) * 256 + tid;        // 4096 blocks, exact cover
    const float4* src = (const float4*)inp + (size_t)idx * 2;
    inpb[idx] = pack8(src[0], src[1]);
  }
}

// Grouped GEMM — minimal staged-bytes config: 128x128 tile, both operands
// bf16, staged total = A 67 + B 67 = 134 MB (vs gemm9's 201). 1-phase
// single-buffer, plain __syncthreads. LDS 32.25 KB; grid 640 (512 active,
// 2/CU, 16 waves/CU — R4-proven tile shape & wave layout).
// bid = e + 8*(nt + 4*mt): e -> XCD (B_e L2-hot); nt-siblings share A in L2.
// A & B identical staging geometry (8 chunks/row of 16B, 4 sites each),
// swizzle both-sides clog = c ^ (row&7) (proven R4/R11/R14).
__global__ __launch_bounds__(256, 4)
void moe_gemm10(const short* __restrict__ inpb, const short* __restrict__ wbf,
                const int* __restrict__ cursor, const int* __restrict__ perm,
                float* __restrict__ out) {
  const int bid = blockIdx.x;
  const int e  = bid & 7;
  const int nt = (bid >> 3) & 3;
  const int mt = bid >> 5;
  const int cnt = cursor[e];
  if (mt * BM >= cnt) return;
  const int m_valid = min(BM, cnt - mt * BM);
  const int* pb = perm + e * EROWS + mt * BM;

  __shared__ __align__(16) char Albs[BM * BK * 2];   // 16 KB bf16 A
  __shared__ __align__(16) char Blbs[BN * BK * 2];   // 16 KB bf16 B
  __shared__ int toks[BM];

  const int tid = threadIdx.x;
  if (tid < BM) toks[tid] = pb[(tid < m_valid) ? tid : 0];
  __syncthreads();

  const int lane = tid & 63;
  const int wid  = tid >> 6;
  const int wr = wid >> 1, wc = wid & 1;   // 2x2 wave grid of 64x64 quadrants
  const int lr = lane & 15;
  const int lg = lane >> 4;

  // ---- A DMA geometry: 4 sites; chunk = s*256+tid -> row = s*32+(tid>>3),
  //      cphys = tid&7; source clog = cphys ^ (row&7); dest linear.
  const short* agp[4];
#pragma unroll
  for (int s = 0; s < 4; s++) {
    int row  = s * 32 + (tid >> 3);
    int clog = (tid & 7) ^ (row & 7);
    agp[s] = inpb + (size_t)toks[row] * INF + clog * 8;
  }

  // ---- B DMA geometry (identical pattern) ----
  const short* Wbase = wbf + ((size_t)e * OUTF + (size_t)nt * BN) * INF;
  const short* bgp[4];
#pragma unroll
  for (int s = 0; s < 4; s++) {
    int row  = s * 32 + (tid >> 3);
    int clog = (tid & 7) ^ (row & 7);
    bgp[s] = Wbase + (size_t)row * INF + clog * 8;
  }

  f32x4 acc[4][4];
#pragma unroll
  for (int i = 0; i < 4; i++)
#pragma unroll
    for (int j = 0; j < 4; j++) acc[i][j] = (f32x4)0.0f;

  for (int t = 0; t < NST; t++) {
    // ---- stage tile t (8 homogeneous gload16/thread) ----
#pragma unroll
    for (int s = 0; s < 4; s++)
      gload16(agp[s] + t * BK, Albs + s * 4096 + tid * 16);
#pragma unroll
    for (int s = 0; s < 4; s++)
      gload16(bgp[s] + t * BK, Blbs + s * 4096 + tid * 16);
    __syncthreads();   // drain DMA

    // ---- compute (2 ks x 4 i x 4 j = 32 MFMA/wave, R4 layout) ----
#pragma unroll
    for (int ks = 0; ks < 2; ks++) {
      bfrag af[4], bv[4];
#pragma unroll
      for (int i = 0; i < 4; i++) {
        int row = wr * 64 + i * 16 + lr;
        int c = (ks * 4 + lg) ^ (row & 7);
        af[i] = *(const bfrag*)(Albs + row * 128 + c * 16);
      }
#pragma unroll
      for (int j = 0; j < 4; j++) {
        int row = wc * 64 + j * 16 + lr;
        int c = (ks * 4 + lg) ^ (row & 7);
        bv[j] = *(const bfrag*)(Blbs + row * 128 + c * 16);
      }
#pragma unroll
      for (int i = 0; i < 4; i++)
#pragma unroll
        for (int j = 0; j < 4; j++)
          acc[i][j] = __builtin_amdgcn_mfma_f32_16x16x32_bf16(af[i], bv[j],
                                                              acc[i][j], 0, 0, 0);
    }
    if (t + 1 < NST) __syncthreads();  // reads done before next overwrite
  }

  // ---- epilogue: C/D col=lane&15, row=(lane>>4)*4+reg (R4-proven) ----
#pragma unroll
  for (int i = 0; i < 4; i++) {
    int rbase = wr * 64 + i * 16 + lg * 4;
#pragma unroll
    for (int r = 0; r < 4; r++) {
      int rr = rbase + r;
      if (rr < m_valid) {
        float* orow = out + (size_t)toks[rr] * OUTF + (size_t)nt * BN +
                      (size_t)wc * 64 + lr;
#pragma unroll
        for (int j = 0; j < 4; j++) orow[j * 16] = acc[i][j][r];
      }
    }
  }
}

extern "C" void kernel_launch(void* const* d_in, const int* in_sizes, int n_in,
                              void* d_out, int out_size, void* d_ws, size_t ws_size,
                              hipStream_t stream) {
  (void)in_sizes; (void)n_in; (void)out_size; (void)ws_size;
  const float* inp    = (const float*)d_in[0];
  const int*   gate   = (const int*)d_in[1];
  const float* weight = (const float*)d_in[2];
  float* out = (float*)d_out;

  char* ws = (char*)d_ws;
  int*   cursor = (int*)ws;                    // 64 B
  int*   perm   = (int*)(ws + 4096);           // 8*2560*4 = 80 KB
  short* wbf    = (short*)(ws + (1 << 20));    // 4 MB bf16 weight
  short* inpb   = (short*)(ws + (8 << 20));    // 16.7 MB bf16 inp (token order)

  hipMemsetAsync(cursor, 0, 64, stream);
  k_prep<<<1088 + (TOKENS * INF) / (256 * 8), 256, 0, stream>>>(
      gate, cursor, perm, weight, (s8v*)wbf, inp, (s8v*)inpb);
  moe_gemm10<<<NEXP * 4 * MAXMT, 256, 0, stream>>>(inpb, wbf, cursor, perm, out);
}

// Round 16
// 35.368 us; speedup vs baseline: 4.2174x; 1.0321x over previous
//
#include <hip/hip_runtime.h>
#include <hip/hip_bf16.h>

#define TOKENS 16384
#define NEXP 8
#define INF 512
#define OUTF 512

#define BM 64
#define BN 128
#define BK 64
#define NST (INF / BK)     // 8 K-steps
#define MAXMT 40           // 2560 rows/expert; counts ~2048±42(σ) -> +12σ safe
#define EROWS (MAXMT * BM)

using f32x4 = __attribute__((ext_vector_type(4))) float;
using bfrag = __attribute__((ext_vector_type(8))) __bf16;
using s8v   = __attribute__((ext_vector_type(8))) short;

// fp32 -> bf16 RNE
__device__ __forceinline__ short f2bf(float f) {
  union { float f; unsigned u; } v; v.f = f;
  unsigned r = v.u + 0x7fffu + ((v.u >> 16) & 1u);
  return (short)(r >> 16);
}

__device__ __forceinline__ void gload16(const void* g, void* l) {
  __builtin_amdgcn_global_load_lds(
      (const __attribute__((address_space(1))) unsigned int*)g,
      (__attribute__((address_space(3))) unsigned int*)l, 16, 0, 0);
}

__device__ __forceinline__ s8v pack8(float4 a, float4 b) {
  s8v p;
  p[0] = f2bf(a.x); p[1] = f2bf(a.y); p[2] = f2bf(a.z); p[3] = f2bf(a.w);
  p[4] = f2bf(b.x); p[5] = f2bf(b.y); p[6] = f2bf(b.z); p[7] = f2bf(b.w);
  return p;
}

__device__ __forceinline__ bfrag cvt8(f32x4 lo, f32x4 hi) {
  bfrag r;
  r[0] = (__bf16)lo[0]; r[1] = (__bf16)lo[1];
  r[2] = (__bf16)lo[2]; r[3] = (__bf16)lo[3];
  r[4] = (__bf16)hi[0]; r[5] = (__bf16)hi[1];
  r[6] = (__bf16)hi[2]; r[7] = (__bf16)hi[3];
  return r;
}

// Fused: blocks 0..63 scatter tokens by expert; blocks 64..1087 convert
// weight fp32 -> bf16 (contiguous [E][O][I]). Cursor pre-zeroed by memset.
__global__ void k_prep(const int* __restrict__ gate, int* __restrict__ cursor,
                       int* __restrict__ perm, const float* __restrict__ w,
                       s8v* __restrict__ wb) {
  __shared__ int lc[NEXP], lb[NEXP];
  const int bid = blockIdx.x, tid = threadIdx.x;
  if (bid < 64) {
    if (tid < NEXP) lc[tid] = 0;
    __syncthreads();
    int t = bid * 256 + tid;
    int e = gate[t];
    int ls = atomicAdd(&lc[e], 1);
    __syncthreads();
    if (tid < NEXP) lb[tid] = lc[tid] ? atomicAdd(&cursor[tid], lc[tid]) : 0;
    __syncthreads();
    perm[e * EROWS + lb[e] + ls] = t;
  } else {
    int idx = (bid - 64) * 256 + tid;
    const float4* src = (const float4*)w + (size_t)idx * 2;
    wb[idx] = pack8(src[0], src[1]);
  }
}

// Grouped GEMM (R11 champion, verbatim): 64x128 tile, ~1024 active blocks
// (4/CU, 16 waves/CU), 1-phase single-buffer, plain __syncthreads (no manual
// waitcnt). Cross-block overlap hides the per-step drain (m114).
// bid = e + 8*(nt + 4*mt): e -> XCD (B_e L2-hot); the 4 nt-siblings of one
// A-tile dispatch back-to-back on the SAME XCD -> A re-reads are L2 hits.
// A staged fp32 (cvt8 at fragment read); B bf16 (k_prep).
// Swizzles both-sides (rule #21): A clog=c^(row&15); B clog=c^(row&7).
__global__ __launch_bounds__(256, 4)
void moe_gemm7(const float* __restrict__ inp, const short* __restrict__ wbf,
               const int* __restrict__ cursor, const int* __restrict__ perm,
               float* __restrict__ out) {
  const int bid = blockIdx.x;
  const int e  = bid & 7;
  const int nt = (bid >> 3) & 3;
  const int mt = bid >> 5;
  const int cnt = cursor[e];
  if (mt * BM >= cnt) return;
  const int m_valid = min(BM, cnt - mt * BM);
  const int* pb = perm + e * EROWS + mt * BM;

  __shared__ __align__(16) char Albs[BM * BK * 4];   // 16 KB fp32 A
  __shared__ __align__(16) char Blbs[BN * BK * 2];   // 16 KB bf16 B
  __shared__ int toks[BM];

  const int tid = threadIdx.x;
  if (tid < BM) toks[tid] = pb[(tid < m_valid) ? tid : 0];
  __syncthreads();

  const int lane = tid & 63;
  const int wid  = tid >> 6;
  const int wr = wid >> 1, wc = wid & 1;   // wave: rows wr*32..+31, cols wc*64..+63
  const int lr = lane & 15;
  const int lg = lane >> 4;

  // ---- A DMA geometry: 4 sites; chunk = s*256+tid -> row = s*16+(tid>>4),
  //      cphys = tid&15; source clog = cphys ^ (row&15); dest linear.
  const float* agp[4];
#pragma unroll
  for (int s = 0; s < 4; s++) {
    int row  = s * 16 + (tid >> 4);
    int clog = (tid & 15) ^ (row & 15);
    agp[s] = inp + (size_t)toks[row] * INF + clog * 4;
  }

  // ---- B DMA geometry: 4 sites; chunk = s*256+tid -> row = s*32+(tid>>3),
  //      cphys = tid&7; source clog = cphys ^ (row&7); dest linear.
  const short* Wbase = wbf + ((size_t)e * OUTF + (size_t)nt * BN) * INF;
  const short* bgp[4];
#pragma unroll
  for (int s = 0; s < 4; s++) {
    int row  = s * 32 + (tid >> 3);
    int clog = (tid & 7) ^ (row & 7);
    bgp[s] = Wbase + (size_t)row * INF + clog * 8;
  }

  f32x4 acc[2][4];
#pragma unroll
  for (int m = 0; m < 2; m++)
#pragma unroll
    for (int j = 0; j < 4; j++) acc[m][j] = (f32x4)0.0f;

  for (int t = 0; t < NST; t++) {
    // ---- stage tile t (8 homogeneous gload16/thread) ----
#pragma unroll
    for (int s = 0; s < 4; s++)
      gload16(agp[s] + t * BK, Albs + s * 4096 + tid * 16);
#pragma unroll
    for (int s = 0; s < 4; s++)
      gload16(bgp[s] + t * BK, Blbs + s * 4096 + tid * 16);
    __syncthreads();   // drain DMA

    // ---- compute (2 ks x 2 m x 4 n = 16 MFMA/wave) ----
#pragma unroll
    for (int ks = 0; ks < 2; ks++) {
      bfrag af[2], bv[4];
#pragma unroll
      for (int m = 0; m < 2; m++) {
        int row = wr * 32 + m * 16 + lr;
        int c0 = (ks * 8 + lg * 2) ^ (row & 15);
        int c1 = (ks * 8 + lg * 2 + 1) ^ (row & 15);
        f32x4 lo = *(const f32x4*)(Albs + row * 256 + c0 * 16);
        f32x4 hi = *(const f32x4*)(Albs + row * 256 + c1 * 16);
        af[m] = cvt8(lo, hi);
      }
#pragma unroll
      for (int j = 0; j < 4; j++) {
        int row = wc * 64 + j * 16 + lr;
        int c = (ks * 4 + lg) ^ (row & 7);
        bv[j] = *(const bfrag*)(Blbs + row * 128 + c * 16);
      }
#pragma unroll
      for (int m = 0; m < 2; m++)
#pragma unroll
        for (int j = 0; j < 4; j++)
          acc[m][j] = __builtin_amdgcn_mfma_f32_16x16x32_bf16(af[m], bv[j],
                                                              acc[m][j], 0, 0, 0);
    }
    if (t + 1 < NST) __syncthreads();  // reads done before next overwrite
  }

  // ---- epilogue: C/D col=lane&15, row=(lane>>4)*4+reg (proven) ----
#pragma unroll
  for (int m = 0; m < 2; m++) {
#pragma unroll
    for (int r = 0; r < 4; r++) {
      int rowE = wr * 32 + m * 16 + lg * 4 + r;
      if (rowE < m_valid) {
        float* orow = out + (size_t)toks[rowE] * OUTF + (size_t)nt * BN +
                      (size_t)wc * 64 + lr;
#pragma unroll
        for (int j = 0; j < 4; j++) orow[j * 16] = acc[m][j][r];
      }
    }
  }
}

extern "C" void kernel_launch(void* const* d_in, const int* in_sizes, int n_in,
                              void* d_out, int out_size, void* d_ws, size_t ws_size,
                              hipStream_t stream) {
  (void)in_sizes; (void)n_in; (void)out_size; (void)ws_size;
  const float* inp    = (const float*)d_in[0];
  const int*   gate   = (const int*)d_in[1];
  const float* weight = (const float*)d_in[2];
  float* out = (float*)d_out;

  char* ws = (char*)d_ws;
  int*   cursor = (int*)ws;                    // 64 B
  int*   perm   = (int*)(ws + 4096);           // 8*2560*4 = 80 KB
  short* wbf    = (short*)(ws + (1 << 20));    // 4 MB bf16 weight

  hipMemsetAsync(cursor, 0, 64, stream);       // replaces k_zero launch
  k_prep<<<64 + (NEXP * OUTF * INF) / (256 * 8), 256, 0, stream>>>(
      gate, cursor, perm, weight, (s8v*)wbf);
  moe_gemm7<<<NEXP * 4 * MAXMT, 256, 0, stream>>>(inp, wbf, cursor, perm, out);
}